// Round 1
// baseline (109.434 us; speedup 1.0000x reference)
//
#include <hip/hip_runtime.h>
#include <math.h>

// Strategy: force = MLP(|dr|) is a piecewise-linear scalar function of the
// scalar edge length. Build a dense fp32 lookup table of force(d) on
// [0, R] (R = 2*max||x|| >= any possible pairwise distance), then the edge
// pass is gather + lerp + atomic scatter. Turns 5e10 FLOP into ~5e8 FLOP.

#define M_TAB 8192
#define EPSF 1e-12f

// K0: out[i] = -gamma * v[i]; also zero the dmax scratch slot.
__global__ __launch_bounds__(256) void k0_init(const float* __restrict__ v,
                                               const float* __restrict__ gamma,
                                               float* __restrict__ out,
                                               unsigned* __restrict__ wsu,
                                               int n) {
  int i = blockIdx.x * blockDim.x + threadIdx.x;
  if (i == 0) wsu[0] = 0u;
  if (i < n) out[i] = -gamma[0] * v[i];
}

// K1: max over nodes of ||x_i||^2 -> wsu[0] (uint-ordered atomicMax, valid
// since values are non-negative).
__global__ __launch_bounds__(256) void k1_maxnorm(const float* __restrict__ x,
                                                  unsigned* __restrict__ wsu,
                                                  int n) {
  __shared__ float red[256];
  int tid = threadIdx.x;
  float m = 0.f;
  for (int i = blockIdx.x * blockDim.x + tid; i < n;
       i += gridDim.x * blockDim.x) {
    float2 p = ((const float2*)x)[i];
    m = fmaxf(m, fmaf(p.x, p.x, p.y * p.y));
  }
  red[tid] = m;
  __syncthreads();
  for (int s = 128; s > 0; s >>= 1) {
    if (tid < s) red[tid] = fmaxf(red[tid], red[tid + s]);
    __syncthreads();
  }
  if (tid == 0) atomicMax(wsu, __float_as_uint(red[0]));
}

// K2: build table[i] = MLP(i * R/(M_TAB-1)) in exact fp32.
// Block = 128 threads (thread j = neuron j), 8 grid points per block held in
// registers; hidden vectors staged in LDS [k][p] so each k-iteration reads
// them as two broadcast float4s. Weights streamed from global (L2-hot).
__global__ __launch_bounds__(128) void k2_table(
    const float* __restrict__ W0, const float* __restrict__ b0,
    const float* __restrict__ W1, const float* __restrict__ b1,
    const float* __restrict__ W2, const float* __restrict__ b2,
    const float* __restrict__ W3, const float* __restrict__ b3,
    const unsigned* __restrict__ wsu, float* __restrict__ table) {
  __shared__ float bufA[128 * 8];
  __shared__ float bufB[128 * 8];
  const int j = threadIdx.x;
  const float R = 2.f * sqrtf(__uint_as_float(wsu[0]));
  const float step = R / (float)(M_TAB - 1);
  const int base = blockIdx.x * 8;

  // L0: 1 -> 128, ReLU
  {
    float w = W0[j], b = b0[j];
#pragma unroll
    for (int p = 0; p < 8; ++p)
      bufA[j * 8 + p] = fmaxf(fmaf((float)(base + p) * step, w, b), 0.f);
  }
  __syncthreads();

  float acc[8];
  // L1: 128 -> 128, ReLU  (reads bufA, writes bufB)
  {
    float b = b1[j];
#pragma unroll
    for (int p = 0; p < 8; ++p) acc[p] = b;
#pragma unroll 8
    for (int k = 0; k < 128; ++k) {
      float w = W1[k * 128 + j];
      float4 h0 = *(const float4*)&bufA[k * 8];
      float4 h1 = *(const float4*)&bufA[k * 8 + 4];
      acc[0] = fmaf(h0.x, w, acc[0]);
      acc[1] = fmaf(h0.y, w, acc[1]);
      acc[2] = fmaf(h0.z, w, acc[2]);
      acc[3] = fmaf(h0.w, w, acc[3]);
      acc[4] = fmaf(h1.x, w, acc[4]);
      acc[5] = fmaf(h1.y, w, acc[5]);
      acc[6] = fmaf(h1.z, w, acc[6]);
      acc[7] = fmaf(h1.w, w, acc[7]);
    }
#pragma unroll
    for (int p = 0; p < 8; ++p) bufB[j * 8 + p] = fmaxf(acc[p], 0.f);
  }
  __syncthreads();

  // L2: 128 -> 128, ReLU (reads bufB), then multiply by W3[j] and stash the
  // per-thread partial products into bufA for the final reduction.
  {
    float b = b2[j];
#pragma unroll
    for (int p = 0; p < 8; ++p) acc[p] = b;
#pragma unroll 8
    for (int k = 0; k < 128; ++k) {
      float w = W2[k * 128 + j];
      float4 h0 = *(const float4*)&bufB[k * 8];
      float4 h1 = *(const float4*)&bufB[k * 8 + 4];
      acc[0] = fmaf(h0.x, w, acc[0]);
      acc[1] = fmaf(h0.y, w, acc[1]);
      acc[2] = fmaf(h0.z, w, acc[2]);
      acc[3] = fmaf(h0.w, w, acc[3]);
      acc[4] = fmaf(h1.x, w, acc[4]);
      acc[5] = fmaf(h1.y, w, acc[5]);
      acc[6] = fmaf(h1.z, w, acc[6]);
      acc[7] = fmaf(h1.w, w, acc[7]);
    }
    float w3 = W3[j];
#pragma unroll
    for (int p = 0; p < 8; ++p) bufA[j * 8 + p] = fmaxf(acc[p], 0.f) * w3;
  }
  __syncthreads();

  // Tree-reduce the 128 partials for each of the 8 points.
  for (int s = 64; s > 0; s >>= 1) {
    if (j < s) {
#pragma unroll
      for (int p = 0; p < 8; ++p)
        bufA[j * 8 + p] += bufA[(j + s) * 8 + p];
    }
    __syncthreads();
  }
  if (j < 8) table[base + j] = bufA[j] + b3[0];
}

// K3: per-edge gather -> distance -> table lerp -> atomic scatter-add.
__global__ __launch_bounds__(256) void k3_edges(
    const float* __restrict__ x, const int* __restrict__ src,
    const int* __restrict__ dst, const float* __restrict__ table,
    const unsigned* __restrict__ wsu, float* __restrict__ out, int E) {
  int e = blockIdx.x * blockDim.x + threadIdx.x;
  if (e >= E) return;
  int s = src[e], t = dst[e];
  float2 xs = ((const float2*)x)[s];
  float2 xt = ((const float2*)x)[t];
  float dx = xt.x - xs.x, dy = xt.y - xs.y;
  float d = sqrtf(fmaf(dx, dx, dy * dy));
  float R = 2.f * sqrtf(__uint_as_float(wsu[0]));
  float step = R / (float)(M_TAB - 1);
  float u = d / step;
  u = fminf(u, (float)(M_TAB - 1));
  int i0 = (int)u;
  if (i0 > M_TAB - 2) i0 = M_TAB - 2;
  float frac = u - (float)i0;
  float f0 = table[i0], f1 = table[i0 + 1];
  float f = fmaf(frac, f1 - f0, f0);
  float sc = f / fmaxf(d, EPSF);
  atomicAdd(&out[2 * t + 0], sc * dx);
  atomicAdd(&out[2 * t + 1], sc * dy);
}

extern "C" void kernel_launch(void* const* d_in, const int* in_sizes, int n_in,
                              void* d_out, int out_size, void* d_ws,
                              size_t ws_size, hipStream_t stream) {
  const float* x = (const float*)d_in[0];
  const float* v = (const float*)d_in[1];
  const int* src = (const int*)d_in[2];
  const int* dst = (const int*)d_in[3];
  const float* gamma = (const float*)d_in[4];
  const float* W0 = (const float*)d_in[5];
  const float* b0 = (const float*)d_in[6];
  const float* W1 = (const float*)d_in[7];
  const float* b1 = (const float*)d_in[8];
  const float* W2 = (const float*)d_in[9];
  const float* b2 = (const float*)d_in[10];
  const float* W3 = (const float*)d_in[11];
  const float* b3 = (const float*)d_in[12];
  float* out = (float*)d_out;
  unsigned* wsu = (unsigned*)d_ws;
  float* table = (float*)((char*)d_ws + 256);

  int n_out = out_size;           // 200000
  int n_nodes = in_sizes[0] / 2;  // 100000
  int E = in_sizes[2];            // 800000

  hipLaunchKernelGGL(k0_init, dim3((n_out + 255) / 256), dim3(256), 0, stream,
                     v, gamma, out, wsu, n_out);
  hipLaunchKernelGGL(k1_maxnorm, dim3(128), dim3(256), 0, stream, x, wsu,
                     n_nodes);
  hipLaunchKernelGGL(k2_table, dim3(M_TAB / 8), dim3(128), 0, stream, W0, b0,
                     W1, b1, W2, b2, W3, b3, wsu, table);
  hipLaunchKernelGGL(k3_edges, dim3((E + 255) / 256), dim3(256), 0, stream, x,
                     src, dst, table, wsu, out, E);
}